// Round 3
// baseline (189.645 us; speedup 1.0000x reference)
//
#include <hip/hip_runtime.h>

typedef __bf16 v8bf __attribute__((ext_vector_type(8)));
typedef float v4f __attribute__((ext_vector_type(4)));
typedef unsigned int v4u __attribute__((ext_vector_type(4)));
typedef unsigned int v2u __attribute__((ext_vector_type(2)));
typedef unsigned short u16;

#define DEVI static __device__ __forceinline__

DEVI float bf2f(u16 u) {
    union { float f; unsigned int i; } c; c.i = ((unsigned int)u) << 16; return c.f;
}
DEVI u16 f2bf(float f) {
    union { float f; unsigned int i; } c; c.f = f;
    unsigned int i = c.i;
    i += 0x7fffu + ((i >> 16) & 1u);   // RNE
    return (u16)(i >> 16);
}

union Frag { v4u u; v8bf v; u16 h[8]; };

#define GLD16(gptr, lptr) __builtin_amdgcn_global_load_lds( \
    (const __attribute__((address_space(1))) void*)(gptr),  \
    (__attribute__((address_space(3))) void*)(lptr), 16, 0, 0)

// ---------------------------------------------------------------------------
// fp32 -> bf16 convert: seg 0: x (4096x1024) -> xb
//                       seg 1: Wq (1024x1024) -> wb[0:]
//                       seg 2: Wk (256x1024)  -> wb[1024*1024:]
//                       seg 3: Wv (256x1024)  -> wb[1280*1024:]
//                       seg 4: Wo (1024x1024) -> wob
// ---------------------------------------------------------------------------
__global__ __launch_bounds__(256) void convert5(
    const float* __restrict__ x, const float* __restrict__ wq,
    const float* __restrict__ wk, const float* __restrict__ wv,
    const float* __restrict__ wo, u16* __restrict__ xb,
    u16* __restrict__ wb, u16* __restrict__ wob)
{
    const float* src; u16* dst; int n;
    switch (blockIdx.y) {
        case 0: src = x;  dst = xb;               n = 4096 * 1024; break;
        case 1: src = wq; dst = wb;               n = 1024 * 1024; break;
        case 2: src = wk; dst = wb + 1024 * 1024; n = 256 * 1024;  break;
        case 3: src = wv; dst = wb + 1280 * 1024; n = 256 * 1024;  break;
        default: src = wo; dst = wob;             n = 1024 * 1024; break;
    }
    const int stride = gridDim.x * 256 * 4;
    for (int i = (blockIdx.x * 256 + threadIdx.x) * 4; i < n; i += stride) {
        const float4 f = *(const float4*)(src + i);
        v2u p;
        p[0] = (unsigned int)f2bf(f.x) | ((unsigned int)f2bf(f.y) << 16);
        p[1] = (unsigned int)f2bf(f.z) | ((unsigned int)f2bf(f.w) << 16);
        *(v2u*)(dst + i) = p;
    }
}

// ---------------------------------------------------------------------------
// GEMM: C[M,N] = A[M,K](bf16) * B[N,K]^T(bf16)   (M=4096, K=1024 fixed)
// Output fp32 (F32OUT) or bf16. m97 recipe: 128x128 tile, BK=32,
// global_load_lds w=16, 16x16x32 bf16 MFMA.
// ---------------------------------------------------------------------------
template <bool F32OUT>
__global__ __launch_bounds__(256) void gemm_bt(
    const u16* __restrict__ A, const u16* __restrict__ B,
    void* __restrict__ Cv, int N)
{
    __shared__ __align__(16) u16 As[128 * 32];
    __shared__ __align__(16) u16 Bs[128 * 32];
    const int tid  = threadIdx.x;
    const int lane = tid & 63, l15 = lane & 15, quad = lane >> 4;
    const int w    = tid >> 6;
    const int wr   = (w >> 1) * 64, wc = (w & 1) * 64;
    const int m0   = blockIdx.y * 128, n0 = blockIdx.x * 128;

    const u16* ab = A + m0 * 1024;
    const u16* bb = B + n0 * 1024;

    const int r0 = tid >> 2;          // row 0..63 (and +64)
    const int c0 = (tid & 3) * 8;     // col chunk
    const u16* ag = ab + r0 * 1024 + c0;
    const u16* bg = bb + r0 * 1024 + c0;
    u16* al = &As[r0 * 32 + c0];      // per-lane offset = lane*16B within wave (lds-dma ok)
    u16* bl = &Bs[r0 * 32 + c0];

    v4f acc[4][4];
    const v4f vzero = {0.f, 0.f, 0.f, 0.f};
#pragma unroll
    for (int i = 0; i < 4; i++)
#pragma unroll
        for (int j = 0; j < 4; j++) acc[i][j] = vzero;

    for (int k0 = 0; k0 < 1024; k0 += 32) {
        __syncthreads();
        GLD16(ag + k0,             al);
        GLD16(ag + k0 + 64 * 1024, al + 64 * 32);
        GLD16(bg + k0,             bl);
        GLD16(bg + k0 + 64 * 1024, bl + 64 * 32);
        __syncthreads();
        v8bf af[4];
#pragma unroll
        for (int mi = 0; mi < 4; mi++)
            af[mi] = *(const v8bf*)&As[(wr + mi * 16 + l15) * 32 + quad * 8];
#pragma unroll
        for (int ni = 0; ni < 4; ni++) {
            v8bf bv = *(const v8bf*)&Bs[(wc + ni * 16 + l15) * 32 + quad * 8];
#pragma unroll
            for (int mi = 0; mi < 4; mi++)
                acc[mi][ni] = __builtin_amdgcn_mfma_f32_16x16x32_bf16(af[mi], bv, acc[mi][ni], 0, 0, 0);
        }
    }
#pragma unroll
    for (int mi = 0; mi < 4; mi++) {
        const int row = m0 + wr + mi * 16 + quad * 4;
#pragma unroll
        for (int ni = 0; ni < 4; ni++) {
            const int col = n0 + wc + ni * 16 + l15;
#pragma unroll
            for (int r = 0; r < 4; r++) {
                if (F32OUT) ((float*)Cv)[(row + r) * N + col] = acc[mi][ni][r];
                else        ((u16*)Cv)[(row + r) * N + col] = f2bf(acc[mi][ni][r]);
            }
        }
    }
}

// ---------------------------------------------------------------------------
// Fixup: gate+ve on v, RoPE + RMS-norm(*1.2) on q,k.  One block per token.
// 8 half-waves x 3 iters = 24 tasks: 16 q-heads, 4 k-heads, 4 v-heads.
// qkv is bf16 (GEMM out); x/ve/cos/sin/Wg are fp32; outputs bf16.
// ---------------------------------------------------------------------------
__global__ __launch_bounds__(256) void fixup(
    const u16* __restrict__ qkv, const float* __restrict__ x,
    const float* __restrict__ ve, const float* __restrict__ cs,
    const float* __restrict__ sn, const float* __restrict__ Wg,
    u16* __restrict__ qn, u16* __restrict__ kn, u16* __restrict__ vn)
{
    const int token = blockIdx.x;
    const int pos   = token & 1023;
    const int tid   = threadIdx.x;
    const int hw    = tid >> 5, l = tid & 31;
    const float c = cs[pos * 32 + l];
    const float s = sn[pos * 32 + l];
#pragma unroll
    for (int it = 0; it < 3; it++) {
        const int task = it * 8 + hw;   // wave-uniform branch (tasks pair up per wave)
        if (task < 20) {
            const u16* src; u16* dst;
            if (task < 16) { src = qkv + token * 1536 + task * 64;               dst = qn + token * 1024 + task * 64; }
            else           { src = qkv + token * 1536 + 1024 + (task - 16) * 64; dst = kn + token * 256 + (task - 16) * 64; }
            const float x1 = bf2f(src[l]), x2 = bf2f(src[32 + l]);
            const float y1 = x1 * c + x2 * s;
            const float y2 = x2 * c - x1 * s;
            float ss = y1 * y1 + y2 * y2;
#pragma unroll
            for (int off = 16; off >= 1; off >>= 1) ss += __shfl_xor(ss, off, 64);
            const float inv = rsqrtf(ss * (1.0f / 64.0f) + 1.1920929e-7f) * 1.2f;
            dst[l]      = f2bf(y1 * inv);
            dst[32 + l] = f2bf(y2 * inv);
        } else {
            const int g = task - 20;
            float dot = 0.f;
#pragma unroll
            for (int cc = 0; cc < 12; cc++)
                dot += x[token * 1024 + cc] * Wg[g * 12 + cc];
            const float gate = 3.f / (1.f + __expf(-dot));
            const u16*  vsrc  = qkv + token * 1536 + 1280 + g * 64;
            const float* vesrc = ve + token * 256 + g * 64;
            u16* vdst = vn + token * 256 + g * 64;
            vdst[l]      = f2bf(bf2f(vsrc[l])      + gate * vesrc[l]);
            vdst[32 + l] = f2bf(bf2f(vsrc[32 + l]) + gate * vesrc[32 + l]);
        }
    }
}

// ---------------------------------------------------------------------------
// Sliding-window flash attention (all-bf16 internal). Block = (b, g, 64-query
// tile); wave w = rep r. K tiles full 64 keys, every row has >=1 valid key.
// QK^T and PV via 16x16x32 bf16 MFMA; P: C-layout -> LDS -> A-layout;
// V transposed in LDS (stride 72).
// ---------------------------------------------------------------------------
__global__ __launch_bounds__(256) void attn(
    const u16* __restrict__ qn, const u16* __restrict__ kn,
    const u16* __restrict__ vn, u16* __restrict__ yo)
{
    __shared__ __align__(16) u16 Ks[64 * 72];
    __shared__ __align__(16) u16 VTs[64 * 72];
    __shared__ __align__(16) u16 Ps[4][64 * 72];
    const int tid  = threadIdx.x;
    const int w    = tid >> 6, lane = tid & 63, l15 = lane & 15, quad = lane >> 4;
    const int qb   = blockIdx.x & 15, g = (blockIdx.x >> 4) & 3, b = blockIdx.x >> 6;
    const int h    = g * 4 + w;
    const int qbase = qb * 64;
    const int tok0  = b * 1024 + qbase;
    u16* pw = Ps[w];

    // Q fragments, pre-scaled by 1/sqrt(64)=0.125 (exact in bf16)
    v8bf qf[4][2];
#pragma unroll
    for (int mi = 0; mi < 4; mi++)
#pragma unroll
        for (int ks = 0; ks < 2; ks++) {
            Frag f;
            f.u = *(const v4u*)&qn[(tok0 + mi * 16 + l15) * 1024 + h * 64 + ks * 32 + quad * 8];
#pragma unroll
            for (int j = 0; j < 8; j++) f.h[j] = f2bf(0.125f * bf2f(f.h[j]));
            qf[mi][ks] = f.v;
        }

    v4f o[4][4];
    float mi_[4][4], li_[4][4];
    const v4f vzero = {0.f, 0.f, 0.f, 0.f};
#pragma unroll
    for (int a = 0; a < 4; a++)
#pragma unroll
        for (int d = 0; d < 4; d++) o[a][d] = vzero;
#pragma unroll
    for (int a = 0; a < 4; a++)
#pragma unroll
        for (int r = 0; r < 4; r++) { mi_[a][r] = -1e38f; li_[a][r] = 0.f; }

    const int kstart = (qbase >= 256) ? qbase - 256 : 0;
    for (int kbase = kstart; kbase <= qbase; kbase += 64) {
        __syncthreads();   // protect K/VT from previous iteration's PV reads
        {
            // full 64x64 coverage: 256 threads x 16 elements
            const int row = tid >> 2, ch = (tid & 3) * 16;
            const int goff = (b * 1024 + kbase + row) * 256 + g * 64 + ch;
            *(v4u*)&Ks[row * 72 + ch]     = *(const v4u*)&kn[goff];
            *(v4u*)&Ks[row * 72 + ch + 8] = *(const v4u*)&kn[goff + 8];
            Frag fv0; fv0.u = *(const v4u*)&vn[goff];
            Frag fv1; fv1.u = *(const v4u*)&vn[goff + 8];
#pragma unroll
            for (int j = 0; j < 8; j++) {
                VTs[(ch + j) * 72 + row]     = fv0.h[j];
                VTs[(ch + 8 + j) * 72 + row] = fv1.h[j];
            }
        }
        __syncthreads();

        v8bf kf[4][2];
#pragma unroll
        for (int ni = 0; ni < 4; ni++)
#pragma unroll
            for (int ks = 0; ks < 2; ks++)
                kf[ni][ks] = *(const v8bf*)&Ks[(ni * 16 + l15) * 72 + ks * 32 + quad * 8];

#pragma unroll
        for (int mi = 0; mi < 4; mi++) {
            v4f sc[4];
#pragma unroll
            for (int ni = 0; ni < 4; ni++) {
                v4f a = vzero;
                a = __builtin_amdgcn_mfma_f32_16x16x32_bf16(qf[mi][0], kf[ni][0], a, 0, 0, 0);
                a = __builtin_amdgcn_mfma_f32_16x16x32_bf16(qf[mi][1], kf[ni][1], a, 0, 0, 0);
                sc[ni] = a;
            }
            const int qi0 = qbase + mi * 16 + quad * 4;
#pragma unroll
            for (int ni = 0; ni < 4; ni++) {
                const int kj = kbase + ni * 16 + l15;
#pragma unroll
                for (int r = 0; r < 4; r++) {
                    const int qi = qi0 + r;
                    if (!((kj <= qi) && (qi - kj <= 256))) sc[ni][r] = -1e30f;
                }
            }
            float rmax[4], mn[4], alp[4], ps[4];
#pragma unroll
            for (int r = 0; r < 4; r++)
                rmax[r] = fmaxf(fmaxf(sc[0][r], sc[1][r]), fmaxf(sc[2][r], sc[3][r]));
#pragma unroll
            for (int off = 8; off >= 1; off >>= 1)
#pragma unroll
                for (int r = 0; r < 4; r++)
                    rmax[r] = fmaxf(rmax[r], __shfl_xor(rmax[r], off, 64));
#pragma unroll
            for (int r = 0; r < 4; r++) {
                mn[r]  = fmaxf(mi_[mi][r], rmax[r]);
                alp[r] = __expf(mi_[mi][r] - mn[r]);
                mi_[mi][r] = mn[r];
                ps[r] = 0.f;
            }
#pragma unroll
            for (int ni = 0; ni < 4; ni++)
#pragma unroll
                for (int r = 0; r < 4; r++) {
                    const float p = __expf(sc[ni][r] - mn[r]);
                    ps[r] += p;
                    pw[(mi * 16 + quad * 4 + r) * 72 + ni * 16 + l15] = f2bf(p);
                }
#pragma unroll
            for (int off = 8; off >= 1; off >>= 1)
#pragma unroll
                for (int r = 0; r < 4; r++)
                    ps[r] += __shfl_xor(ps[r], off, 64);
#pragma unroll
            for (int r = 0; r < 4; r++)
                li_[mi][r] = li_[mi][r] * alp[r] + ps[r];
#pragma unroll
            for (int ni = 0; ni < 4; ni++)
#pragma unroll
                for (int r = 0; r < 4; r++)
                    o[mi][ni][r] *= alp[r];
        }
        __syncthreads();   // QK reads of Ks done before next staging

#pragma unroll
        for (int ks = 0; ks < 2; ks++) {
            v8bf af[4];
#pragma unroll
            for (int mi = 0; mi < 4; mi++)
                af[mi] = *(const v8bf*)&pw[(mi * 16 + l15) * 72 + ks * 32 + quad * 8];
#pragma unroll
            for (int ni = 0; ni < 4; ni++) {
                v8bf bv = *(const v8bf*)&VTs[(ni * 16 + l15) * 72 + ks * 32 + quad * 8];
#pragma unroll
                for (int mi = 0; mi < 4; mi++)
                    o[mi][ni] = __builtin_amdgcn_mfma_f32_16x16x32_bf16(af[mi], bv, o[mi][ni], 0, 0, 0);
            }
        }
    }

#pragma unroll
    for (int mi = 0; mi < 4; mi++) {
        float inv[4];
#pragma unroll
        for (int r = 0; r < 4; r++) inv[r] = 1.f / li_[mi][r];
#pragma unroll
        for (int ni = 0; ni < 4; ni++) {
            const int col = h * 64 + ni * 16 + l15;
#pragma unroll
            for (int r = 0; r < 4; r++) {
                const int row = tok0 + mi * 16 + quad * 4 + r;
                yo[row * 1024 + col] = f2bf(o[mi][ni][r] * inv[r]);
            }
        }
    }
}

// ---------------------------------------------------------------------------
extern "C" void kernel_launch(void* const* d_in, const int* in_sizes, int n_in,
                              void* d_out, int out_size, void* d_ws, size_t ws_size,
                              hipStream_t stream)
{
    const float* x  = (const float*)d_in[0];
    const float* ve = (const float*)d_in[1];
    const float* cs = (const float*)d_in[2];
    const float* sn = (const float*)d_in[3];
    const float* Wq = (const float*)d_in[4];
    const float* Wk = (const float*)d_in[5];
    const float* Wv = (const float*)d_in[6];
    const float* Wo = (const float*)d_in[7];
    const float* Wg = (const float*)d_in[8];
    // d_in[9] = window_size (fixed 256, hard-coded)

    u16* xb  = (u16*)d_ws;              // 4096 x 1024 bf16 x
    u16* wb  = xb  + 4096 * 1024;       // 1536 x 1024 bf16 [Wq;Wk;Wv]
    u16* wob = wb  + 1536 * 1024;       // 1024 x 1024 bf16 Wo
    u16* qkv = wob + 1024 * 1024;       // 4096 x 1536 (dead after fixup)
    u16* qn  = qkv + 4096 * 1536;       // 4096 x 1024
    u16* kn  = qn  + 4096 * 1024;       // 4096 x 256
    u16* vn  = kn  + 4096 * 256;        // 4096 x 256
    u16* ay  = qkv;                     // attention out aliases dead qkv

    convert5<<<dim3(512, 5), 256, 0, stream>>>(x, Wq, Wk, Wv, Wo, xb, wb, wob);
    gemm_bt<false><<<dim3(12, 32), 256, 0, stream>>>(xb, wb, (void*)qkv, 1536);
    fixup<<<4096, 256, 0, stream>>>(qkv, x, ve, cs, sn, Wg, qn, kn, vn);
    attn<<<256, 256, 0, stream>>>(qn, kn, vn, ay);
    gemm_bt<true><<<dim3(8, 32), 256, 0, stream>>>(ay, wob, d_out, 1024);
}

// Round 4
// 180.089 us; speedup vs baseline: 1.0531x; 1.0531x over previous
//
#include <hip/hip_runtime.h>

typedef __bf16 v8bf __attribute__((ext_vector_type(8)));
typedef float v4f __attribute__((ext_vector_type(4)));
typedef unsigned int v4u __attribute__((ext_vector_type(4)));
typedef unsigned int v2u __attribute__((ext_vector_type(2)));
typedef unsigned short u16;

#define DEVI static __device__ __forceinline__

DEVI float bf2f(u16 u) {
    union { float f; unsigned int i; } c; c.i = ((unsigned int)u) << 16; return c.f;
}
DEVI u16 f2bf(float f) {
    union { float f; unsigned int i; } c; c.f = f;
    unsigned int i = c.i;
    i += 0x7fffu + ((i >> 16) & 1u);   // RNE
    return (u16)(i >> 16);
}

union Frag { v4u u; v8bf v; u16 h[8]; };

#define GLD16(gptr, lptr) __builtin_amdgcn_global_load_lds( \
    (const __attribute__((address_space(1))) void*)(gptr),  \
    (__attribute__((address_space(3))) void*)(lptr), 16, 0, 0)

// ---------------------------------------------------------------------------
// fp32 -> bf16 convert: x, Wq, Wk, Wv packed, Wo
// ---------------------------------------------------------------------------
__global__ __launch_bounds__(256) void convert5(
    const float* __restrict__ x, const float* __restrict__ wq,
    const float* __restrict__ wk, const float* __restrict__ wv,
    const float* __restrict__ wo, u16* __restrict__ xb,
    u16* __restrict__ wb, u16* __restrict__ wob)
{
    const float* src; u16* dst; int n;
    switch (blockIdx.y) {
        case 0: src = x;  dst = xb;               n = 4096 * 1024; break;
        case 1: src = wq; dst = wb;               n = 1024 * 1024; break;
        case 2: src = wk; dst = wb + 1024 * 1024; n = 256 * 1024;  break;
        case 3: src = wv; dst = wb + 1280 * 1024; n = 256 * 1024;  break;
        default: src = wo; dst = wob;             n = 1024 * 1024; break;
    }
    const int stride = gridDim.x * 256 * 4;
    for (int i = (blockIdx.x * 256 + threadIdx.x) * 4; i < n; i += stride) {
        const float4 f = *(const float4*)(src + i);
        v2u p;
        p[0] = (unsigned int)f2bf(f.x) | ((unsigned int)f2bf(f.y) << 16);
        p[1] = (unsigned int)f2bf(f.z) | ((unsigned int)f2bf(f.w) << 16);
        *(v2u*)(dst + i) = p;
    }
}

// ---------------------------------------------------------------------------
// GEMM: C[M,N] = A[M,K](bf16) * B[N,K]^T(bf16)   (M=4096, K=1024 fixed)
// m97 recipe: 128x128 tile, BK=32, global_load_lds w=16, 16x16x32 bf16 MFMA
// ---------------------------------------------------------------------------
template <bool F32OUT>
__global__ __launch_bounds__(256) void gemm_bt(
    const u16* __restrict__ A, const u16* __restrict__ B,
    void* __restrict__ Cv, int N)
{
    __shared__ __align__(16) u16 As[128 * 32];
    __shared__ __align__(16) u16 Bs[128 * 32];
    const int tid  = threadIdx.x;
    const int lane = tid & 63, l15 = lane & 15, quad = lane >> 4;
    const int w    = tid >> 6;
    const int wr   = (w >> 1) * 64, wc = (w & 1) * 64;
    const int m0   = blockIdx.y * 128, n0 = blockIdx.x * 128;

    const u16* ab = A + m0 * 1024;
    const u16* bb = B + n0 * 1024;

    const int r0 = tid >> 2;
    const int c0 = (tid & 3) * 8;
    const u16* ag = ab + r0 * 1024 + c0;
    const u16* bg = bb + r0 * 1024 + c0;
    u16* al = &As[r0 * 32 + c0];
    u16* bl = &Bs[r0 * 32 + c0];

    v4f acc[4][4];
    const v4f vzero = {0.f, 0.f, 0.f, 0.f};
#pragma unroll
    for (int i = 0; i < 4; i++)
#pragma unroll
        for (int j = 0; j < 4; j++) acc[i][j] = vzero;

    for (int k0 = 0; k0 < 1024; k0 += 32) {
        __syncthreads();
        GLD16(ag + k0,             al);
        GLD16(ag + k0 + 64 * 1024, al + 64 * 32);
        GLD16(bg + k0,             bl);
        GLD16(bg + k0 + 64 * 1024, bl + 64 * 32);
        __syncthreads();
        v8bf af[4];
#pragma unroll
        for (int mi = 0; mi < 4; mi++)
            af[mi] = *(const v8bf*)&As[(wr + mi * 16 + l15) * 32 + quad * 8];
#pragma unroll
        for (int ni = 0; ni < 4; ni++) {
            v8bf bv = *(const v8bf*)&Bs[(wc + ni * 16 + l15) * 32 + quad * 8];
#pragma unroll
            for (int mi = 0; mi < 4; mi++)
                acc[mi][ni] = __builtin_amdgcn_mfma_f32_16x16x32_bf16(af[mi], bv, acc[mi][ni], 0, 0, 0);
        }
    }
#pragma unroll
    for (int mi = 0; mi < 4; mi++) {
        const int row = m0 + wr + mi * 16 + quad * 4;
#pragma unroll
        for (int ni = 0; ni < 4; ni++) {
            const int col = n0 + wc + ni * 16 + l15;
#pragma unroll
            for (int r = 0; r < 4; r++) {
                if (F32OUT) ((float*)Cv)[(row + r) * N + col] = acc[mi][ni][r];
                else        ((u16*)Cv)[(row + r) * N + col] = f2bf(acc[mi][ni][r]);
            }
        }
    }
}

// ---------------------------------------------------------------------------
// Fixup: gate+ve on v, RoPE + RMS-norm(*1.2) on q,k.  One block per token.
// ---------------------------------------------------------------------------
__global__ __launch_bounds__(256) void fixup(
    const u16* __restrict__ qkv, const float* __restrict__ x,
    const float* __restrict__ ve, const float* __restrict__ cs,
    const float* __restrict__ sn, const float* __restrict__ Wg,
    u16* __restrict__ qn, u16* __restrict__ kn, u16* __restrict__ vn)
{
    const int token = blockIdx.x;
    const int pos   = token & 1023;
    const int tid   = threadIdx.x;
    const int hw    = tid >> 5, l = tid & 31;
    const float c = cs[pos * 32 + l];
    const float s = sn[pos * 32 + l];
#pragma unroll
    for (int it = 0; it < 3; it++) {
        const int task = it * 8 + hw;
        if (task < 20) {
            const u16* src; u16* dst;
            if (task < 16) { src = qkv + token * 1536 + task * 64;               dst = qn + token * 1024 + task * 64; }
            else           { src = qkv + token * 1536 + 1024 + (task - 16) * 64; dst = kn + token * 256 + (task - 16) * 64; }
            const float x1 = bf2f(src[l]), x2 = bf2f(src[32 + l]);
            const float y1 = x1 * c + x2 * s;
            const float y2 = x2 * c - x1 * s;
            float ss = y1 * y1 + y2 * y2;
#pragma unroll
            for (int off = 16; off >= 1; off >>= 1) ss += __shfl_xor(ss, off, 64);
            const float inv = rsqrtf(ss * (1.0f / 64.0f) + 1.1920929e-7f) * 1.2f;
            dst[l]      = f2bf(y1 * inv);
            dst[32 + l] = f2bf(y2 * inv);
        } else {
            const int g = task - 20;
            float dot = 0.f;
#pragma unroll
            for (int cc = 0; cc < 12; cc++)
                dot += x[token * 1024 + cc] * Wg[g * 12 + cc];
            const float gate = 3.f / (1.f + __expf(-dot));
            const u16*   vsrc  = qkv + token * 1536 + 1280 + g * 64;
            const float* vesrc = ve + token * 256 + g * 64;
            u16* vdst = vn + token * 256 + g * 64;
            vdst[l]      = f2bf(bf2f(vsrc[l])      + gate * vesrc[l]);
            vdst[32 + l] = f2bf(bf2f(vsrc[32 + l]) + gate * vesrc[32 + l]);
        }
    }
}

// ---------------------------------------------------------------------------
// Sliding-window flash attention v2.
// Grid (qb=16, h=16, b=4) = 1024 blocks (4/CU). Wave w owns query rows
// [qb*64 + w*16, +16) of head h. K/V (head group g=h>>2) staged per block.
// Per-wave P slice in LDS (no barrier needed for the C->A layout round-trip;
// same-wave LDS ops are ordered). Wave-uniform block-level mask skips:
// fully-masked (w,ni) blocks skip QK MFMA + exp; fully-valid skip cndmask.
// ---------------------------------------------------------------------------
__global__ __launch_bounds__(256) void attn(
    const u16* __restrict__ qn, const u16* __restrict__ kn,
    const u16* __restrict__ vn, u16* __restrict__ yo)
{
    __shared__ __align__(16) u16 Ks[64 * 72];
    __shared__ __align__(16) u16 VTs[64 * 72];
    __shared__ __align__(16) u16 Ps[4][16 * 72];
    const int tid  = threadIdx.x;
    const int w    = tid >> 6, lane = tid & 63, l15 = lane & 15, quad = lane >> 4;
    const int qb   = blockIdx.x, h = blockIdx.y, b = blockIdx.z;
    const int g    = h >> 2;
    const int qbase = qb * 64;
    const int qabs0 = qbase + w * 16;          // first query row of this wave
    const int tok0  = b * 1024 + qabs0;
    u16* pw = Ps[w];

    // Q fragments (16 rows x 64 d), pre-scaled by 1/8 (exact in bf16)
    v8bf qf[2];
#pragma unroll
    for (int ks = 0; ks < 2; ks++) {
        Frag f;
        f.u = *(const v4u*)&qn[(tok0 + l15) * 1024 + h * 64 + ks * 32 + quad * 8];
#pragma unroll
        for (int j = 0; j < 8; j++) f.h[j] = f2bf(0.125f * bf2f(f.h[j]));
        qf[ks] = f.v;
    }

    v4f o[4];
    float mi_[4], li_[4];
    const v4f vzero = {0.f, 0.f, 0.f, 0.f};
#pragma unroll
    for (int nd = 0; nd < 4; nd++) o[nd] = vzero;
#pragma unroll
    for (int r = 0; r < 4; r++) { mi_[r] = -1e30f; li_[r] = 0.f; }

    const int kstart = (qbase >= 256) ? qbase - 256 : 0;
    for (int kbase = kstart; kbase <= qbase; kbase += 64) {
        __syncthreads();   // previous iteration's K/VT reads complete
        {
            const int row = tid >> 2, ch = (tid & 3) * 16;
            const int goff = (b * 1024 + kbase + row) * 256 + g * 64 + ch;
            *(v4u*)&Ks[row * 72 + ch]     = *(const v4u*)&kn[goff];
            *(v4u*)&Ks[row * 72 + ch + 8] = *(const v4u*)&kn[goff + 8];
            Frag fv0; fv0.u = *(const v4u*)&vn[goff];
            Frag fv1; fv1.u = *(const v4u*)&vn[goff + 8];
#pragma unroll
            for (int j = 0; j < 8; j++) {
                VTs[(ch + j) * 72 + row]     = fv0.h[j];
                VTs[(ch + 8 + j) * 72 + row] = fv1.h[j];
            }
        }
        __syncthreads();

        // wave-uniform per-ni classification
        bool skip[4], full[4];
#pragma unroll
        for (int ni = 0; ni < 4; ni++) {
            const int left = kbase + ni * 16;
            skip[ni] = (left > qabs0 + 15) || (qabs0 - (left + 15) > 256);
            full[ni] = ((left + 15) <= qabs0) && ((qabs0 + 15 - left) <= 256);
        }

        v4f sc[4];
        float rmax[4] = {-1e30f, -1e30f, -1e30f, -1e30f};
#pragma unroll
        for (int ni = 0; ni < 4; ni++) {
            if (skip[ni]) continue;
            v8bf kf0 = *(const v8bf*)&Ks[(ni * 16 + l15) * 72 + quad * 8];
            v8bf kf1 = *(const v8bf*)&Ks[(ni * 16 + l15) * 72 + 32 + quad * 8];
            v4f a = vzero;
            a = __builtin_amdgcn_mfma_f32_16x16x32_bf16(qf[0], kf0, a, 0, 0, 0);
            a = __builtin_amdgcn_mfma_f32_16x16x32_bf16(qf[1], kf1, a, 0, 0, 0);
            if (!full[ni]) {
                const int kj = kbase + ni * 16 + l15;
#pragma unroll
                for (int r = 0; r < 4; r++) {
                    const int qi = qabs0 + quad * 4 + r;
                    if (!((kj <= qi) && (qi - kj <= 256))) a[r] = -1e30f;
                }
            }
            sc[ni] = a;
#pragma unroll
            for (int r = 0; r < 4; r++) rmax[r] = fmaxf(rmax[r], a[r]);
        }
#pragma unroll
        for (int off = 8; off >= 1; off >>= 1)
#pragma unroll
            for (int r = 0; r < 4; r++)
                rmax[r] = fmaxf(rmax[r], __shfl_xor(rmax[r], off, 64));

        float mn[4], alp[4], ps[4];
#pragma unroll
        for (int r = 0; r < 4; r++) {
            mn[r]  = fmaxf(mi_[r], rmax[r]);
            alp[r] = __expf(mi_[r] - mn[r]);
            mi_[r] = mn[r];
            ps[r]  = 0.f;
        }
#pragma unroll
        for (int ni = 0; ni < 4; ni++) {
            if (skip[ni]) {
#pragma unroll
                for (int r = 0; r < 4; r++)
                    pw[(quad * 4 + r) * 72 + ni * 16 + l15] = 0;
            } else {
#pragma unroll
                for (int r = 0; r < 4; r++) {
                    const float p = __expf(sc[ni][r] - mn[r]);
                    ps[r] += p;
                    pw[(quad * 4 + r) * 72 + ni * 16 + l15] = f2bf(p);
                }
            }
        }
#pragma unroll
        for (int off = 8; off >= 1; off >>= 1)
#pragma unroll
            for (int r = 0; r < 4; r++)
                ps[r] += __shfl_xor(ps[r], off, 64);
#pragma unroll
        for (int r = 0; r < 4; r++)
            li_[r] = li_[r] * alp[r] + ps[r];
#pragma unroll
        for (int nd = 0; nd < 4; nd++)
#pragma unroll
            for (int r = 0; r < 4; r++)
                o[nd][r] *= alp[r];

        // PV: same-wave LDS round-trip — compiler's lgkmcnt handles ordering.
#pragma unroll
        for (int ks = 0; ks < 2; ks++) {
            if (skip[2 * ks] && skip[2 * ks + 1]) continue;
            v8bf af = *(const v8bf*)&pw[l15 * 72 + ks * 32 + quad * 8];
#pragma unroll
            for (int nd = 0; nd < 4; nd++) {
                v8bf bv = *(const v8bf*)&VTs[(nd * 16 + l15) * 72 + ks * 32 + quad * 8];
                o[nd] = __builtin_amdgcn_mfma_f32_16x16x32_bf16(af, bv, o[nd], 0, 0, 0);
            }
        }
    }

    float inv[4];
#pragma unroll
    for (int r = 0; r < 4; r++) inv[r] = 1.f / li_[r];
#pragma unroll
    for (int nd = 0; nd < 4; nd++) {
        const int col = h * 64 + nd * 16 + l15;
#pragma unroll
        for (int r = 0; r < 4; r++) {
            const int row = tok0 + quad * 4 + r;
            yo[row * 1024 + col] = f2bf(o[nd][r] * inv[r]);
        }
    }
}

// ---------------------------------------------------------------------------
extern "C" void kernel_launch(void* const* d_in, const int* in_sizes, int n_in,
                              void* d_out, int out_size, void* d_ws, size_t ws_size,
                              hipStream_t stream)
{
    const float* x  = (const float*)d_in[0];
    const float* ve = (const float*)d_in[1];
    const float* cs = (const float*)d_in[2];
    const float* sn = (const float*)d_in[3];
    const float* Wq = (const float*)d_in[4];
    const float* Wk = (const float*)d_in[5];
    const float* Wv = (const float*)d_in[6];
    const float* Wo = (const float*)d_in[7];
    const float* Wg = (const float*)d_in[8];
    // d_in[9] = window_size (fixed 256, hard-coded)

    u16* xb  = (u16*)d_ws;              // 4096 x 1024 bf16 x
    u16* wb  = xb  + 4096 * 1024;       // 1536 x 1024 bf16 [Wq;Wk;Wv]
    u16* wob = wb  + 1536 * 1024;       // 1024 x 1024 bf16 Wo
    u16* qkv = wob + 1024 * 1024;       // 4096 x 1536 (dead after fixup)
    u16* qn  = qkv + 4096 * 1536;       // 4096 x 1024
    u16* kn  = qn  + 4096 * 1024;       // 4096 x 256
    u16* vn  = kn  + 4096 * 256;        // 4096 x 256
    u16* ay  = qkv;                     // attention out aliases dead qkv

    convert5<<<dim3(512, 5), 256, 0, stream>>>(x, Wq, Wk, Wv, Wo, xb, wb, wob);
    gemm_bt<false><<<dim3(12, 32), 256, 0, stream>>>(xb, wb, (void*)qkv, 1536);
    fixup<<<4096, 256, 0, stream>>>(qkv, x, ve, cs, sn, Wg, qn, kn, vn);
    attn<<<dim3(16, 16, 4), 256, 0, stream>>>(qn, kn, vn, ay);
    gemm_bt<true><<<dim3(8, 32), 256, 0, stream>>>(ay, wob, d_out, 1024);
}

// Round 5
// 172.942 us; speedup vs baseline: 1.0966x; 1.0413x over previous
//
#include <hip/hip_runtime.h>

typedef __bf16 v8bf __attribute__((ext_vector_type(8)));
typedef float v4f __attribute__((ext_vector_type(4)));
typedef unsigned int v4u __attribute__((ext_vector_type(4)));
typedef unsigned int v2u __attribute__((ext_vector_type(2)));
typedef unsigned short u16;

#define DEVI static __device__ __forceinline__

DEVI float bf2f(u16 u) {
    union { float f; unsigned int i; } c; c.i = ((unsigned int)u) << 16; return c.f;
}
DEVI u16 f2bf(float f) {
    union { float f; unsigned int i; } c; c.f = f;
    unsigned int i = c.i;
    i += 0x7fffu + ((i >> 16) & 1u);   // RNE
    return (u16)(i >> 16);
}

union Frag { v4u u; v8bf v; u16 h[8]; };

#define GLD16(gptr, lptr) __builtin_amdgcn_global_load_lds( \
    (const __attribute__((address_space(1))) void*)(gptr),  \
    (__attribute__((address_space(3))) void*)(lptr), 16, 0, 0)

// ---------------------------------------------------------------------------
// fp32 -> bf16 convert: x, Wq, Wk, Wv packed, Wo
// ---------------------------------------------------------------------------
__global__ __launch_bounds__(256) void convert5(
    const float* __restrict__ x, const float* __restrict__ wq,
    const float* __restrict__ wk, const float* __restrict__ wv,
    const float* __restrict__ wo, u16* __restrict__ xb,
    u16* __restrict__ wb, u16* __restrict__ wob)
{
    const float* src; u16* dst; int n;
    switch (blockIdx.y) {
        case 0: src = x;  dst = xb;               n = 4096 * 1024; break;
        case 1: src = wq; dst = wb;               n = 1024 * 1024; break;
        case 2: src = wk; dst = wb + 1024 * 1024; n = 256 * 1024;  break;
        case 3: src = wv; dst = wb + 1280 * 1024; n = 256 * 1024;  break;
        default: src = wo; dst = wob;             n = 1024 * 1024; break;
    }
    const int stride = gridDim.x * 256 * 4;
    for (int i = (blockIdx.x * 256 + threadIdx.x) * 4; i < n; i += stride) {
        const float4 f = *(const float4*)(src + i);
        v2u p;
        p[0] = (unsigned int)f2bf(f.x) | ((unsigned int)f2bf(f.y) << 16);
        p[1] = (unsigned int)f2bf(f.z) | ((unsigned int)f2bf(f.w) << 16);
        *(v2u*)(dst + i) = p;
    }
}

// ---------------------------------------------------------------------------
// GEMM: C[M,N] = A[M,K](bf16) * B[N,K]^T(bf16)   (M=4096, K=1024 fixed)
// Tile 64x128, BK=32: grid = (N/128) * 64 blocks -> 2-3 resident blocks/CU
// (fixes the 1-block/CU grid starvation of the 128x128 variant at N<=1536).
// Wave w owns a 32x64 sub-tile: acc 2x4, 8 MFMA : 6 ds_read_b128 per K-step.
// ---------------------------------------------------------------------------
template <bool F32OUT>
__global__ __launch_bounds__(256) void gemm_bt(
    const u16* __restrict__ A, const u16* __restrict__ B,
    void* __restrict__ Cv, int N)
{
    __shared__ __align__(16) u16 As[64 * 32];
    __shared__ __align__(16) u16 Bs[128 * 32];
    const int tid  = threadIdx.x;
    const int lane = tid & 63, l15 = lane & 15, quad = lane >> 4;
    const int w    = tid >> 6;
    const int wr   = (w >> 1) * 32, wc = (w & 1) * 64;
    const int m0   = blockIdx.y * 64, n0 = blockIdx.x * 128;

    const u16* ab = A + m0 * 1024;
    const u16* bb = B + n0 * 1024;

    const int r0 = tid >> 2;          // 0..63
    const int c0 = (tid & 3) * 8;
    const u16* ag = ab + r0 * 1024 + c0;
    const u16* bg = bb + r0 * 1024 + c0;
    u16* al = &As[r0 * 32 + c0];      // per-lane lds offset = lane*16B (lds-dma ok)
    u16* bl = &Bs[r0 * 32 + c0];

    v4f acc[2][4];
    const v4f vzero = {0.f, 0.f, 0.f, 0.f};
#pragma unroll
    for (int i = 0; i < 2; i++)
#pragma unroll
        for (int j = 0; j < 4; j++) acc[i][j] = vzero;

    for (int k0 = 0; k0 < 1024; k0 += 32) {
        __syncthreads();
        GLD16(ag + k0,             al);
        GLD16(bg + k0,             bl);
        GLD16(bg + k0 + 64 * 1024, bl + 64 * 32);
        __syncthreads();
        v8bf af[2];
#pragma unroll
        for (int mi = 0; mi < 2; mi++)
            af[mi] = *(const v8bf*)&As[(wr + mi * 16 + l15) * 32 + quad * 8];
#pragma unroll
        for (int ni = 0; ni < 4; ni++) {
            v8bf bv = *(const v8bf*)&Bs[(wc + ni * 16 + l15) * 32 + quad * 8];
#pragma unroll
            for (int mi = 0; mi < 2; mi++)
                acc[mi][ni] = __builtin_amdgcn_mfma_f32_16x16x32_bf16(af[mi], bv, acc[mi][ni], 0, 0, 0);
        }
    }
#pragma unroll
    for (int mi = 0; mi < 2; mi++) {
        const int row = m0 + wr + mi * 16 + quad * 4;
#pragma unroll
        for (int ni = 0; ni < 4; ni++) {
            const int col = n0 + wc + ni * 16 + l15;
#pragma unroll
            for (int r = 0; r < 4; r++) {
                if (F32OUT) ((float*)Cv)[(row + r) * N + col] = acc[mi][ni][r];
                else        ((u16*)Cv)[(row + r) * N + col] = f2bf(acc[mi][ni][r]);
            }
        }
    }
}

// ---------------------------------------------------------------------------
// Fixup: gate+ve on v, RoPE + RMS-norm(*1.2) on q,k.  One block per token.
// ---------------------------------------------------------------------------
__global__ __launch_bounds__(256) void fixup(
    const u16* __restrict__ qkv, const float* __restrict__ x,
    const float* __restrict__ ve, const float* __restrict__ cs,
    const float* __restrict__ sn, const float* __restrict__ Wg,
    u16* __restrict__ qn, u16* __restrict__ kn, u16* __restrict__ vn)
{
    const int token = blockIdx.x;
    const int pos   = token & 1023;
    const int tid   = threadIdx.x;
    const int hw    = tid >> 5, l = tid & 31;
    const float c = cs[pos * 32 + l];
    const float s = sn[pos * 32 + l];
#pragma unroll
    for (int it = 0; it < 3; it++) {
        const int task = it * 8 + hw;
        if (task < 20) {
            const u16* src; u16* dst;
            if (task < 16) { src = qkv + token * 1536 + task * 64;               dst = qn + token * 1024 + task * 64; }
            else           { src = qkv + token * 1536 + 1024 + (task - 16) * 64; dst = kn + token * 256 + (task - 16) * 64; }
            const float x1 = bf2f(src[l]), x2 = bf2f(src[32 + l]);
            const float y1 = x1 * c + x2 * s;
            const float y2 = x2 * c - x1 * s;
            float ss = y1 * y1 + y2 * y2;
#pragma unroll
            for (int off = 16; off >= 1; off >>= 1) ss += __shfl_xor(ss, off, 64);
            const float inv = rsqrtf(ss * (1.0f / 64.0f) + 1.1920929e-7f) * 1.2f;
            dst[l]      = f2bf(y1 * inv);
            dst[32 + l] = f2bf(y2 * inv);
        } else {
            const int g = task - 20;
            float dot = 0.f;
#pragma unroll
            for (int cc = 0; cc < 12; cc++)
                dot += x[token * 1024 + cc] * Wg[g * 12 + cc];
            const float gate = 3.f / (1.f + __expf(-dot));
            const u16*   vsrc  = qkv + token * 1536 + 1280 + g * 64;
            const float* vesrc = ve + token * 256 + g * 64;
            u16* vdst = vn + token * 256 + g * 64;
            vdst[l]      = f2bf(bf2f(vsrc[l])      + gate * vesrc[l]);
            vdst[32 + l] = f2bf(bf2f(vsrc[32 + l]) + gate * vesrc[32 + l]);
        }
    }
}

// ---------------------------------------------------------------------------
// Sliding-window flash attention v2 (unchanged from round 3).
// Grid (qb=16, h=16, b=4) = 1024 blocks. Wave w owns 16 query rows of head h.
// ---------------------------------------------------------------------------
__global__ __launch_bounds__(256) void attn(
    const u16* __restrict__ qn, const u16* __restrict__ kn,
    const u16* __restrict__ vn, u16* __restrict__ yo)
{
    __shared__ __align__(16) u16 Ks[64 * 72];
    __shared__ __align__(16) u16 VTs[64 * 72];
    __shared__ __align__(16) u16 Ps[4][16 * 72];
    const int tid  = threadIdx.x;
    const int w    = tid >> 6, lane = tid & 63, l15 = lane & 15, quad = lane >> 4;
    const int qb   = blockIdx.x, h = blockIdx.y, b = blockIdx.z;
    const int g    = h >> 2;
    const int qbase = qb * 64;
    const int qabs0 = qbase + w * 16;
    const int tok0  = b * 1024 + qabs0;
    u16* pw = Ps[w];

    v8bf qf[2];
#pragma unroll
    for (int ks = 0; ks < 2; ks++) {
        Frag f;
        f.u = *(const v4u*)&qn[(tok0 + l15) * 1024 + h * 64 + ks * 32 + quad * 8];
#pragma unroll
        for (int j = 0; j < 8; j++) f.h[j] = f2bf(0.125f * bf2f(f.h[j]));
        qf[ks] = f.v;
    }

    v4f o[4];
    float mi_[4], li_[4];
    const v4f vzero = {0.f, 0.f, 0.f, 0.f};
#pragma unroll
    for (int nd = 0; nd < 4; nd++) o[nd] = vzero;
#pragma unroll
    for (int r = 0; r < 4; r++) { mi_[r] = -1e30f; li_[r] = 0.f; }

    const int kstart = (qbase >= 256) ? qbase - 256 : 0;
    for (int kbase = kstart; kbase <= qbase; kbase += 64) {
        __syncthreads();
        {
            const int row = tid >> 2, ch = (tid & 3) * 16;
            const int goff = (b * 1024 + kbase + row) * 256 + g * 64 + ch;
            *(v4u*)&Ks[row * 72 + ch]     = *(const v4u*)&kn[goff];
            *(v4u*)&Ks[row * 72 + ch + 8] = *(const v4u*)&kn[goff + 8];
            Frag fv0; fv0.u = *(const v4u*)&vn[goff];
            Frag fv1; fv1.u = *(const v4u*)&vn[goff + 8];
#pragma unroll
            for (int j = 0; j < 8; j++) {
                VTs[(ch + j) * 72 + row]     = fv0.h[j];
                VTs[(ch + 8 + j) * 72 + row] = fv1.h[j];
            }
        }
        __syncthreads();

        bool skip[4], full[4];
#pragma unroll
        for (int ni = 0; ni < 4; ni++) {
            const int left = kbase + ni * 16;
            skip[ni] = (left > qabs0 + 15) || (qabs0 - (left + 15) > 256);
            full[ni] = ((left + 15) <= qabs0) && ((qabs0 + 15 - left) <= 256);
        }

        v4f sc[4];
        float rmax[4] = {-1e30f, -1e30f, -1e30f, -1e30f};
#pragma unroll
        for (int ni = 0; ni < 4; ni++) {
            if (skip[ni]) continue;
            v8bf kf0 = *(const v8bf*)&Ks[(ni * 16 + l15) * 72 + quad * 8];
            v8bf kf1 = *(const v8bf*)&Ks[(ni * 16 + l15) * 72 + 32 + quad * 8];
            v4f a = vzero;
            a = __builtin_amdgcn_mfma_f32_16x16x32_bf16(qf[0], kf0, a, 0, 0, 0);
            a = __builtin_amdgcn_mfma_f32_16x16x32_bf16(qf[1], kf1, a, 0, 0, 0);
            if (!full[ni]) {
                const int kj = kbase + ni * 16 + l15;
#pragma unroll
                for (int r = 0; r < 4; r++) {
                    const int qi = qabs0 + quad * 4 + r;
                    if (!((kj <= qi) && (qi - kj <= 256))) a[r] = -1e30f;
                }
            }
            sc[ni] = a;
#pragma unroll
            for (int r = 0; r < 4; r++) rmax[r] = fmaxf(rmax[r], a[r]);
        }
#pragma unroll
        for (int off = 8; off >= 1; off >>= 1)
#pragma unroll
            for (int r = 0; r < 4; r++)
                rmax[r] = fmaxf(rmax[r], __shfl_xor(rmax[r], off, 64));

        float mn[4], alp[4], ps[4];
#pragma unroll
        for (int r = 0; r < 4; r++) {
            mn[r]  = fmaxf(mi_[r], rmax[r]);
            alp[r] = __expf(mi_[r] - mn[r]);
            mi_[r] = mn[r];
            ps[r]  = 0.f;
        }
#pragma unroll
        for (int ni = 0; ni < 4; ni++) {
            if (skip[ni]) {
#pragma unroll
                for (int r = 0; r < 4; r++)
                    pw[(quad * 4 + r) * 72 + ni * 16 + l15] = 0;
            } else {
#pragma unroll
                for (int r = 0; r < 4; r++) {
                    const float p = __expf(sc[ni][r] - mn[r]);
                    ps[r] += p;
                    pw[(quad * 4 + r) * 72 + ni * 16 + l15] = f2bf(p);
                }
            }
        }
#pragma unroll
        for (int off = 8; off >= 1; off >>= 1)
#pragma unroll
            for (int r = 0; r < 4; r++)
                ps[r] += __shfl_xor(ps[r], off, 64);
#pragma unroll
        for (int r = 0; r < 4; r++)
            li_[r] = li_[r] * alp[r] + ps[r];
#pragma unroll
        for (int nd = 0; nd < 4; nd++)
#pragma unroll
            for (int r = 0; r < 4; r++)
                o[nd][r] *= alp[r];

#pragma unroll
        for (int ks = 0; ks < 2; ks++) {
            if (skip[2 * ks] && skip[2 * ks + 1]) continue;
            v8bf af = *(const v8bf*)&pw[l15 * 72 + ks * 32 + quad * 8];
#pragma unroll
            for (int nd = 0; nd < 4; nd++) {
                v8bf bv = *(const v8bf*)&VTs[(nd * 16 + l15) * 72 + ks * 32 + quad * 8];
                o[nd] = __builtin_amdgcn_mfma_f32_16x16x32_bf16(af, bv, o[nd], 0, 0, 0);
            }
        }
    }

    float inv[4];
#pragma unroll
    for (int r = 0; r < 4; r++) inv[r] = 1.f / li_[r];
#pragma unroll
    for (int nd = 0; nd < 4; nd++) {
        const int col = h * 64 + nd * 16 + l15;
#pragma unroll
        for (int r = 0; r < 4; r++) {
            const int row = tok0 + quad * 4 + r;
            yo[row * 1024 + col] = f2bf(o[nd][r] * inv[r]);
        }
    }
}

// ---------------------------------------------------------------------------
extern "C" void kernel_launch(void* const* d_in, const int* in_sizes, int n_in,
                              void* d_out, int out_size, void* d_ws, size_t ws_size,
                              hipStream_t stream)
{
    const float* x  = (const float*)d_in[0];
    const float* ve = (const float*)d_in[1];
    const float* cs = (const float*)d_in[2];
    const float* sn = (const float*)d_in[3];
    const float* Wq = (const float*)d_in[4];
    const float* Wk = (const float*)d_in[5];
    const float* Wv = (const float*)d_in[6];
    const float* Wo = (const float*)d_in[7];
    const float* Wg = (const float*)d_in[8];
    // d_in[9] = window_size (fixed 256, hard-coded)

    u16* xb  = (u16*)d_ws;              // 4096 x 1024 bf16 x
    u16* wb  = xb  + 4096 * 1024;       // 1536 x 1024 bf16 [Wq;Wk;Wv]
    u16* wob = wb  + 1536 * 1024;       // 1024 x 1024 bf16 Wo
    u16* qkv = wob + 1024 * 1024;       // 4096 x 1536 (dead after fixup)
    u16* qn  = qkv + 4096 * 1536;       // 4096 x 1024
    u16* kn  = qn  + 4096 * 1024;       // 4096 x 256
    u16* vn  = kn  + 4096 * 256;        // 4096 x 256
    u16* ay  = qkv;                     // attention out aliases dead qkv

    convert5<<<dim3(512, 5), 256, 0, stream>>>(x, Wq, Wk, Wv, Wo, xb, wb, wob);
    gemm_bt<false><<<dim3(12, 64), 256, 0, stream>>>(xb, wb, (void*)qkv, 1536);
    fixup<<<4096, 256, 0, stream>>>(qkv, x, ve, cs, sn, Wg, qn, kn, vn);
    attn<<<dim3(16, 16, 4), 256, 0, stream>>>(qn, kn, vn, ay);
    gemm_bt<true><<<dim3(8, 64), 256, 0, stream>>>(ay, wob, d_out, 1024);
}